// Round 1
// baseline (2916.921 us; speedup 1.0000x reference)
//
#include <hip/hip_runtime.h>

#define EPS 1e-5f
constexpr int NN = 100000;   // nodes
constexpr int NE = 1600000;  // edges
constexpr int R  = 8;

// ---------------- x0 = bn32(emb[n_id]) ----------------
__global__ __launch_bounds__(256) void compute_x0(
    const int* __restrict__ n_id, const float* __restrict__ emb,
    const float* __restrict__ g, const float* __restrict__ b,
    const float* __restrict__ m, const float* __restrict__ v,
    float* __restrict__ x0)
{
    int idx = blockIdx.x * 256 + threadIdx.x;
    if (idx >= NN * 32) return;
    int i = idx >> 5, c = idx & 31;
    float scale = g[c] / sqrtf(v[c] + EPS);
    float x = emb[n_id[i] * 32 + c];
    x0[idx] = (x - m[c]) * scale + b[c];
}

// ---------------- degree per (dst, etype) key ----------------
__global__ __launch_bounds__(256) void deg_count(
    const int* __restrict__ ei, const int* __restrict__ et,
    float* __restrict__ deg)
{
    int e = blockIdx.x * 256 + threadIdx.x;
    if (e >= NE) return;
    int dst = ei[NE + e];
    atomicAdd(&deg[dst * R + et[e]], 1.0f);
}

__global__ __launch_bounds__(256) void deg_invert(float* __restrict__ deg)
{
    int k = blockIdx.x * 256 + threadIdx.x;
    if (k >= NN * R) return;
    deg[k] = 1.0f / fmaxf(deg[k], 1.0f);
}

// ---------------- edge scatter: agg[key][c] += x[src][c] ----------------
template <int CIN>
__global__ __launch_bounds__(256) void edge_agg(
    const int* __restrict__ ei, const int* __restrict__ et,
    const float* __restrict__ x, float* __restrict__ agg)
{
    constexpr int G = CIN / 4;  // float4 groups per edge
    int idx = blockIdx.x * 256 + threadIdx.x;
    if (idx >= NE * G) return;
    int e  = idx / G;
    int c4 = (idx % G) * 4;
    int src = ei[e];
    int dst = ei[NE + e];
    int r   = et[e];
    const float4 xv = *reinterpret_cast<const float4*>(&x[(size_t)src * CIN + c4]);
    float* a = &agg[(size_t)(dst * R + r) * CIN + c4];
    atomicAdd(a + 0, xv.x);
    atomicAdd(a + 1, xv.y);
    atomicAdd(a + 2, xv.z);
    atomicAdd(a + 3, xv.w);
}

// ---------------- fused matmul + epilogue ----------------
// out[i][o] = bn( [relu]( b[o] + sum_c x[i][c]*root[c][o]
//                        + sum_{r,c} agg[i*R+r][c]*inv[i*R+r]*W[r][c][o] ) )
template <int CIN, bool APPLY_RELU>
__global__ __launch_bounds__(256) void fused_matmul(
    const float* __restrict__ x,     // [N, CIN]
    const float* __restrict__ agg,   // [N*R, CIN]
    const float* __restrict__ inv,   // [N*R]
    const float* __restrict__ Wrel,  // [R, CIN, 64] flat
    const float* __restrict__ Wroot, // [CIN, 64]
    const float* __restrict__ bias,  // [64]
    const float* __restrict__ bn_g, const float* __restrict__ bn_b,
    const float* __restrict__ bn_m, const float* __restrict__ bn_v,
    float* __restrict__ out)         // [N, 64]
{
    constexpr int K = CIN + R * CIN;  // 288 or 576
    __shared__ float As[4][K];
    const int node0 = blockIdx.x * 4;
    const int tid = threadIdx.x;

    // stage 4 A-rows: [x_row | inv-scaled agg rows]
    for (int t = tid; t < 4 * K; t += 256) {
        int g = t / K, k = t - g * K;
        int i = node0 + g;
        float val;
        if (k < CIN) {
            val = x[(size_t)i * CIN + k];
        } else {
            int kk = k - CIN;
            int r = kk / CIN;
            int c = kk - r * CIN;
            val = agg[(size_t)(i * R + r) * CIN + c] * inv[i * R + r];
        }
        As[g][k] = val;
    }
    __syncthreads();

    const int g = tid >> 6, o = tid & 63;
    const int i = node0 + g;
    float acc = bias[o];
#pragma unroll 4
    for (int k = 0; k < CIN; ++k)
        acc += As[g][k] * Wroot[k * 64 + o];
#pragma unroll 4
    for (int k = 0; k < R * CIN; ++k)
        acc += As[g][CIN + k] * Wrel[k * 64 + o];

    if (APPLY_RELU) acc = fmaxf(acc, 0.0f);
    float scale = bn_g[o] / sqrtf(bn_v[o] + EPS);
    out[(size_t)i * 64 + o] = (acc - bn_m[o]) * scale + bn_b[o];
}

extern "C" void kernel_launch(void* const* d_in, const int* in_sizes, int n_in,
                              void* d_out, int out_size, void* d_ws, size_t ws_size,
                              hipStream_t stream)
{
    const int*   n_id   = (const int*)d_in[0];
    const int*   ei     = (const int*)d_in[1];   // [2, NE]
    const int*   et     = (const int*)d_in[2];   // [NE]
    const float* emb    = (const float*)d_in[3];
    const float* W1     = (const float*)d_in[4];
    const float* root1  = (const float*)d_in[5];
    const float* b1     = (const float*)d_in[6];
    const float* W2     = (const float*)d_in[7];
    const float* root2  = (const float*)d_in[8];
    const float* b2     = (const float*)d_in[9];
    const float* bn32_g = (const float*)d_in[10];
    const float* bn32_b = (const float*)d_in[11];
    const float* bn32_m = (const float*)d_in[12];
    const float* bn32_v = (const float*)d_in[13];
    const float* bn64_g = (const float*)d_in[14];
    const float* bn64_b = (const float*)d_in[15];
    const float* bn64_m = (const float*)d_in[16];
    const float* bn64_v = (const float*)d_in[17];
    const float* bnb_g  = (const float*)d_in[18];
    const float* bnb_b  = (const float*)d_in[19];
    const float* bnb_m  = (const float*)d_in[20];
    const float* bnb_v  = (const float*)d_in[21];
    float* out = (float*)d_out;

    float* ws  = (float*)d_ws;
    float* deg = ws;                  // [NN*R]        3.2 MB (becomes inv_deg)
    float* x0  = deg + (size_t)NN * R;        // [NN,32]  12.8 MB
    float* h1  = x0 + (size_t)NN * 32;        // [NN,64]  25.6 MB
    float* agg = h1 + (size_t)NN * 64;        // [NN*R,64] max 204.8 MB

    // ---- shared degree (graph identical for both layers) ----
    hipMemsetAsync(deg, 0, (size_t)NN * R * sizeof(float), stream);
    hipMemsetAsync(agg, 0, (size_t)NN * R * 32 * sizeof(float), stream);
    deg_count<<<(NE + 255) / 256, 256, 0, stream>>>(ei, et, deg);
    deg_invert<<<(NN * R + 255) / 256, 256, 0, stream>>>(deg);

    // ---- layer 1 ----
    compute_x0<<<(NN * 32 + 255) / 256, 256, 0, stream>>>(
        n_id, emb, bn32_g, bn32_b, bn32_m, bn32_v, x0);
    edge_agg<32><<<(NE * 8 + 255) / 256, 256, 0, stream>>>(ei, et, x0, agg);
    fused_matmul<32, true><<<NN / 4, 256, 0, stream>>>(
        x0, agg, deg, W1, root1, b1, bn64_g, bn64_b, bn64_m, bn64_v, h1);

    // ---- layer 2 ----
    hipMemsetAsync(agg, 0, (size_t)NN * R * 64 * sizeof(float), stream);
    edge_agg<64><<<(NE * 16 + 255) / 256, 256, 0, stream>>>(ei, et, h1, agg);
    fused_matmul<64, false><<<NN / 4, 256, 0, stream>>>(
        h1, agg, deg, W2, root2, b2, bnb_g, bnb_b, bnb_m, bnb_v, out);
}

// Round 2
// 852.783 us; speedup vs baseline: 3.4205x; 3.4205x over previous
//
#include <hip/hip_runtime.h>

#define EPS 1e-5f
constexpr int NN = 100000;   // nodes
constexpr int NE = 1600000;  // edges
constexpr int R  = 8;
constexpr int NK = NN * R;   // number of (dst, etype) keys
constexpr int SCAN_BLK = 1024;                       // items per scan block
constexpr int NSB = (NK + SCAN_BLK - 1) / SCAN_BLK;  // 782 scan blocks

// ---------------- x0 = bn32(emb[n_id]) ----------------
__global__ __launch_bounds__(256) void compute_x0(
    const int* __restrict__ n_id, const float* __restrict__ emb,
    const float* __restrict__ g, const float* __restrict__ b,
    const float* __restrict__ m, const float* __restrict__ v,
    float* __restrict__ x0)
{
    int idx = blockIdx.x * 256 + threadIdx.x;
    if (idx >= NN * 32) return;
    int i = idx >> 5, c = idx & 31;
    float scale = g[c] / sqrtf(v[c] + EPS);
    float x = emb[n_id[i] * 32 + c];
    x0[idx] = (x - m[c]) * scale + b[c];
}

// ---------------- counting sort of edges by key = dst*R + etype ----------------
__global__ __launch_bounds__(256) void hist_edges(
    const int* __restrict__ ei, const int* __restrict__ et, int* __restrict__ cnt)
{
    int e = blockIdx.x * 256 + threadIdx.x;
    if (e >= NE) return;
    atomicAdd(&cnt[ei[NE + e] * R + et[e]], 1);
}

// block-level exclusive scan: each block scans SCAN_BLK items (4/thread)
__global__ __launch_bounds__(256) void scan_blocks(
    const int* __restrict__ cnt, int* __restrict__ off, int* __restrict__ bsum)
{
    __shared__ int s[256];
    int blk = blockIdx.x, t = threadIdx.x;
    int base = blk * SCAN_BLK + t * 4;
    int v[4];
    int sum = 0;
#pragma unroll
    for (int j = 0; j < 4; ++j) {
        int idx = base + j;
        v[j] = (idx < NK) ? cnt[idx] : 0;
        sum += v[j];
    }
    s[t] = sum;
    __syncthreads();
    for (int d = 1; d < 256; d <<= 1) {   // Hillis-Steele inclusive scan
        int x = (t >= d) ? s[t - d] : 0;
        __syncthreads();
        s[t] += x;
        __syncthreads();
    }
    int run = s[t] - sum;                 // exclusive prefix of this thread
    if (t == 255) bsum[blk] = s[255];
#pragma unroll
    for (int j = 0; j < 4; ++j) {
        int idx = base + j;
        if (idx < NK) off[idx] = run;
        run += v[j];
    }
}

__global__ __launch_bounds__(1024) void scan_bsum(int* __restrict__ bsum)
{
    __shared__ int s[1024];
    int t = threadIdx.x;
    int v = (t < NSB) ? bsum[t] : 0;
    s[t] = v;
    __syncthreads();
    for (int d = 1; d < 1024; d <<= 1) {
        int x = (t >= d) ? s[t - d] : 0;
        __syncthreads();
        s[t] += x;
        __syncthreads();
    }
    if (t < NSB) bsum[t] = s[t] - v;      // exclusive
}

__global__ __launch_bounds__(256) void scan_add(
    int* __restrict__ off, const int* __restrict__ bsum)
{
    int idx = blockIdx.x * 256 + threadIdx.x;
    if (idx > NK) return;
    if (idx == NK) { off[NK] = NE; return; }
    off[idx] += bsum[idx / SCAN_BLK];
}

__global__ __launch_bounds__(256) void scatter_edges(
    const int* __restrict__ ei, const int* __restrict__ et,
    int* __restrict__ cursor, int* __restrict__ ssrc)
{
    int e = blockIdx.x * 256 + threadIdx.x;
    if (e >= NE) return;
    int key = ei[NE + e] * R + et[e];
    int pos = atomicAdd(&cursor[key], 1);
    ssrc[pos] = ei[e];
}

// ---------------- fused gather-aggregate + matmul + epilogue ----------------
// out[i][o] = bn( [relu]( b[o] + sum_c x[i][c]*root[c][o]
//                        + sum_{r,c} mean_{j in bucket(i,r)} x[j][c] * W[r][c][o] ) )
template <int CIN, bool APPLY_RELU>
__global__ __launch_bounds__(256) void fused_layer(
    const float* __restrict__ x,      // [N, CIN]
    const int* __restrict__ off,      // [NK+1]
    const int* __restrict__ ssrc,     // [NE] src ids sorted by key
    const float* __restrict__ Wrel,   // [R, CIN, 64] flat
    const float* __restrict__ Wroot,  // [CIN, 64]
    const float* __restrict__ bias,   // [64]
    const float* __restrict__ bn_g, const float* __restrict__ bn_b,
    const float* __restrict__ bn_m, const float* __restrict__ bn_v,
    float* __restrict__ out)          // [N, 64]
{
    constexpr int NB = 8;             // nodes per block
    constexpr int K = 9 * CIN;        // 288 or 576
    constexpr int NPG = 256 / CIN;    // nodes handled per aggregation pass
    __shared__ float As[NB][K];
    const int node0 = blockIdx.x * NB;
    const int tid = threadIdx.x;

    // ---- phase 1: gather + mean-aggregate into LDS ----
    const int c = tid % CIN;
    const int gg = tid / CIN;
    for (int g = gg; g < NB; g += NPG) {
        const int i = node0 + g;
        As[g][c] = x[(size_t)i * CIN + c];
        const int base = i * R;
#pragma unroll
        for (int r = 0; r < R; ++r) {
            int s = off[base + r], e = off[base + r + 1];
            float acc = 0.0f;
            for (int j = s; j < e; ++j)
                acc += x[(size_t)ssrc[j] * CIN + c];
            float inv = 1.0f / (float)max(e - s, 1);
            As[g][CIN + r * CIN + c] = acc * inv;
        }
    }
    __syncthreads();

    // ---- phase 2: dense [NB x K] * [K x 64] matmul, 2 nodes per thread ----
    const int o = tid & 63;
    const int gb = tid >> 6;          // 0..3 -> nodes gb and gb+4
    float acc0 = bias[o];
    float acc1 = bias[o];
#pragma unroll 4
    for (int k = 0; k < CIN; ++k) {
        float w = Wroot[k * 64 + o];
        acc0 += As[gb][k] * w;
        acc1 += As[gb + 4][k] * w;
    }
#pragma unroll 4
    for (int k = 0; k < 8 * CIN; ++k) {
        float w = Wrel[k * 64 + o];
        acc0 += As[gb][CIN + k] * w;
        acc1 += As[gb + 4][CIN + k] * w;
    }

    if (APPLY_RELU) { acc0 = fmaxf(acc0, 0.0f); acc1 = fmaxf(acc1, 0.0f); }
    float scale = bn_g[o] / sqrtf(bn_v[o] + EPS);
    float mm = bn_m[o], bb = bn_b[o];
    out[(size_t)(node0 + gb) * 64 + o]     = (acc0 - mm) * scale + bb;
    out[(size_t)(node0 + gb + 4) * 64 + o] = (acc1 - mm) * scale + bb;
}

extern "C" void kernel_launch(void* const* d_in, const int* in_sizes, int n_in,
                              void* d_out, int out_size, void* d_ws, size_t ws_size,
                              hipStream_t stream)
{
    const int*   n_id   = (const int*)d_in[0];
    const int*   ei     = (const int*)d_in[1];   // [2, NE]
    const int*   et     = (const int*)d_in[2];   // [NE]
    const float* emb    = (const float*)d_in[3];
    const float* W1     = (const float*)d_in[4];
    const float* root1  = (const float*)d_in[5];
    const float* b1     = (const float*)d_in[6];
    const float* W2     = (const float*)d_in[7];
    const float* root2  = (const float*)d_in[8];
    const float* b2     = (const float*)d_in[9];
    const float* bn32_g = (const float*)d_in[10];
    const float* bn32_b = (const float*)d_in[11];
    const float* bn32_m = (const float*)d_in[12];
    const float* bn32_v = (const float*)d_in[13];
    const float* bn64_g = (const float*)d_in[14];
    const float* bn64_b = (const float*)d_in[15];
    const float* bn64_m = (const float*)d_in[16];
    const float* bn64_v = (const float*)d_in[17];
    const float* bnb_g  = (const float*)d_in[18];
    const float* bnb_b  = (const float*)d_in[19];
    const float* bnb_m  = (const float*)d_in[20];
    const float* bnb_v  = (const float*)d_in[21];
    float* out = (float*)d_out;

    // workspace layout (all 4-byte elements)
    int*   cursor = (int*)d_ws;                       // [NK]   (hist counts, then cursors)
    int*   off    = cursor + NK;                      // [NK+1]
    int*   bsum   = off + NK + 1;                     // [NSB]
    int*   ssrc   = bsum + NSB;                       // [NE]
    float* x0     = (float*)(ssrc + NE);              // [NN,32]
    float* h1     = x0 + (size_t)NN * 32;             // [NN,64]

    // ---- build sorted edge structure (shared by both layers) ----
    hipMemsetAsync(cursor, 0, (size_t)NK * sizeof(int), stream);
    hist_edges<<<(NE + 255) / 256, 256, 0, stream>>>(ei, et, cursor);
    scan_blocks<<<NSB, 256, 0, stream>>>(cursor, off, bsum);
    scan_bsum<<<1, 1024, 0, stream>>>(bsum);
    scan_add<<<(NK + 256) / 256, 256, 0, stream>>>(off, bsum);
    hipMemcpyAsync(cursor, off, (size_t)NK * sizeof(int),
                   hipMemcpyDeviceToDevice, stream);
    scatter_edges<<<(NE + 255) / 256, 256, 0, stream>>>(ei, et, cursor, ssrc);

    // ---- layer 1 ----
    compute_x0<<<(NN * 32 + 255) / 256, 256, 0, stream>>>(
        n_id, emb, bn32_g, bn32_b, bn32_m, bn32_v, x0);
    fused_layer<32, true><<<NN / 8, 256, 0, stream>>>(
        x0, off, ssrc, W1, root1, b1, bn64_g, bn64_b, bn64_m, bn64_v, h1);

    // ---- layer 2 ----
    fused_layer<64, false><<<NN / 8, 256, 0, stream>>>(
        h1, off, ssrc, W2, root2, b2, bnb_g, bnb_b, bnb_m, bnb_v, out);
}

// Round 3
// 441.809 us; speedup vs baseline: 6.6022x; 1.9302x over previous
//
#include <hip/hip_runtime.h>

#define EPS 1e-5f
constexpr int NN = 100000;   // nodes
constexpr int NE = 1600000;  // edges
constexpr int R  = 8;
constexpr int NK = NN * R;   // number of (dst, etype) keys
constexpr int SCAN_BLK = 1024;                       // items per scan block
constexpr int NSB = (NK + SCAN_BLK - 1) / SCAN_BLK;  // 782 scan blocks

typedef _Float16 half8 __attribute__((ext_vector_type(8)));
typedef float f32x4 __attribute__((ext_vector_type(4)));

static __device__ inline float h2f(unsigned short u) {
    _Float16 h = __builtin_bit_cast(_Float16, u);
    return (float)h;
}
static __device__ inline unsigned short f2h(float f) {
    _Float16 h = (_Float16)f;
    return __builtin_bit_cast(unsigned short, h);
}

// ---------------- x0 = bn32(emb[n_id]) -> fp16 ----------------
__global__ __launch_bounds__(256) void compute_x0(
    const int* __restrict__ n_id, const float* __restrict__ emb,
    const float* __restrict__ g, const float* __restrict__ b,
    const float* __restrict__ m, const float* __restrict__ v,
    unsigned int* __restrict__ x0)   // [NN*16] uints = [NN,32] fp16
{
    int idx = blockIdx.x * 256 + threadIdx.x;
    if (idx >= NN * 16) return;
    int i = idx >> 4, c = (idx & 15) * 2;
    int nid = n_id[i];
    float2 e = *reinterpret_cast<const float2*>(&emb[nid * 32 + c]);
    float s0 = g[c]     / sqrtf(v[c]     + EPS);
    float s1 = g[c + 1] / sqrtf(v[c + 1] + EPS);
    float y0 = (e.x - m[c])     * s0 + b[c];
    float y1 = (e.y - m[c + 1]) * s1 + b[c + 1];
    x0[idx] = (unsigned int)f2h(y0) | ((unsigned int)f2h(y1) << 16);
}

// ---------------- counting sort of edges by key = dst*R + etype ----------------
__global__ __launch_bounds__(256) void hist_edges(
    const int* __restrict__ ei, const int* __restrict__ et, int* __restrict__ cnt)
{
    int e = blockIdx.x * 256 + threadIdx.x;
    if (e >= NE) return;
    atomicAdd(&cnt[ei[NE + e] * R + et[e]], 1);
}

__global__ __launch_bounds__(256) void scan_blocks(
    const int* __restrict__ cnt, int* __restrict__ off, int* __restrict__ bsum)
{
    __shared__ int s[256];
    int blk = blockIdx.x, t = threadIdx.x;
    int base = blk * SCAN_BLK + t * 4;
    int v[4];
    int sum = 0;
#pragma unroll
    for (int j = 0; j < 4; ++j) {
        int idx = base + j;
        v[j] = (idx < NK) ? cnt[idx] : 0;
        sum += v[j];
    }
    s[t] = sum;
    __syncthreads();
    for (int d = 1; d < 256; d <<= 1) {
        int x = (t >= d) ? s[t - d] : 0;
        __syncthreads();
        s[t] += x;
        __syncthreads();
    }
    int run = s[t] - sum;
    if (t == 255) bsum[blk] = s[255];
#pragma unroll
    for (int j = 0; j < 4; ++j) {
        int idx = base + j;
        if (idx < NK) off[idx] = run;
        run += v[j];
    }
}

__global__ __launch_bounds__(1024) void scan_bsum(int* __restrict__ bsum)
{
    __shared__ int s[1024];
    int t = threadIdx.x;
    int v = (t < NSB) ? bsum[t] : 0;
    s[t] = v;
    __syncthreads();
    for (int d = 1; d < 1024; d <<= 1) {
        int x = (t >= d) ? s[t - d] : 0;
        __syncthreads();
        s[t] += x;
        __syncthreads();
    }
    if (t < NSB) bsum[t] = s[t] - v;
}

__global__ __launch_bounds__(256) void scan_add(
    int* __restrict__ off, const int* __restrict__ bsum)
{
    int idx = blockIdx.x * 256 + threadIdx.x;
    if (idx > NK) return;
    if (idx == NK) { off[NK] = NE; return; }
    off[idx] += bsum[idx / SCAN_BLK];
}

__global__ __launch_bounds__(256) void scatter_edges(
    const int* __restrict__ ei, const int* __restrict__ et,
    int* __restrict__ cursor, int* __restrict__ ssrc)
{
    int e = blockIdx.x * 256 + threadIdx.x;
    if (e >= NE) return;
    int key = ei[NE + e] * R + et[e];
    int pos = atomicAdd(&cursor[key], 1);
    ssrc[pos] = ei[e];
}

// ---------------- weight pack: B[K,64] fp32 -> fp16 fragments ----------------
// Bp[((t*KS + s)*64 + lane)*8 + j] = B[s*32 + (lane>>4)*8 + j][t*16 + (lane&15)]
template <int CIN>
__global__ __launch_bounds__(256) void pack_B(
    const float* __restrict__ Wrel,   // [R*CIN, 64]
    const float* __restrict__ Wroot,  // [CIN, 64]
    unsigned short* __restrict__ Bp)
{
    constexpr int K = 9 * CIN, KS = K / 32;
    int idx = blockIdx.x * 256 + threadIdx.x;
    if (idx >= 4 * KS * 64) return;
    int l = idx & 63;
    int rest = idx >> 6;
    int s = rest % KS;
    int t = rest / KS;
    int kb = s * 32 + (l >> 4) * 8;
    int col = t * 16 + (l & 15);
    unsigned short* dst = &Bp[(size_t)idx * 8];
#pragma unroll
    for (int j = 0; j < 8; ++j) {
        int k = kb + j;
        float w = (k < CIN) ? Wroot[k * 64 + col]
                            : Wrel[(size_t)(k - CIN) * 64 + col];
        dst[j] = f2h(w);
    }
}

// ---------------- fold BN into scale/shift ----------------
__global__ __launch_bounds__(64) void prep_scales(
    const float* g1, const float* b1, const float* m1, const float* v1,
    float* sc1, float* sh1,
    const float* g2, const float* b2, const float* m2, const float* v2,
    float* sc2, float* sh2)
{
    int o = threadIdx.x;
    float s1 = g1[o] / sqrtf(v1[o] + EPS);
    sc1[o] = s1;
    sh1[o] = b1[o] - m1[o] * s1;
    float s2 = g2[o] / sqrtf(v2[o] + EPS);
    sc2[o] = s2;
    sh2[o] = b2[o] - m2[o] * s2;
}

// ---------------- fused gather-aggregate + MFMA matmul + epilogue ----------------
template <int CIN, bool APPLY_RELU, bool OUT_F16>
__global__ __launch_bounds__(256) void fused_layer(
    const unsigned short* __restrict__ x,   // [N, CIN] fp16
    const int* __restrict__ off,            // [NK+1]
    const int* __restrict__ ssrc,           // [NE]
    const unsigned short* __restrict__ Bp,  // packed fp16 fragments
    const float* __restrict__ bias,         // [64]
    const float* __restrict__ scale, const float* __restrict__ shift,
    void* __restrict__ outv)                // [N,64] fp16 or fp32
{
    constexpr int NB = 16;            // nodes per block (= MFMA M)
    constexpr int K  = 9 * CIN;       // 288 or 576
    constexpr int KS = K / 32;        // MFMA K-steps
    constexpr int Kp = K + 8;         // padded row (2-way banks max)
    __shared__ unsigned short As[NB][Kp];
    const int node0 = blockIdx.x * NB;
    const int tid = threadIdx.x;

    // ---- phase 1: gather + mean-aggregate (fp32 acc) -> fp16 LDS rows ----
    constexpr int GS = CIN / 2;       // lanes per node (2 ch per lane)
    constexpr int NG = 256 / GS;      // nodes in flight
    const int l2 = tid % GS;
    const int g0 = tid / GS;
    for (int g = g0; g < NB; g += NG) {
        const int i = node0 + g;
        // root part: passthrough copy of x row
        *reinterpret_cast<unsigned int*>(&As[g][2 * l2]) =
            *reinterpret_cast<const unsigned int*>(&x[(size_t)i * CIN + 2 * l2]);
        const int base = i * R;
#pragma unroll
        for (int r = 0; r < R; ++r) {
            int s = off[base + r], e = off[base + r + 1];
            float a0 = 0.0f, a1 = 0.0f;
            for (int j = s; j < e; ++j) {
                unsigned int v = *reinterpret_cast<const unsigned int*>(
                    &x[(size_t)ssrc[j] * CIN + 2 * l2]);
                a0 += h2f((unsigned short)(v & 0xffff));
                a1 += h2f((unsigned short)(v >> 16));
            }
            float inv = 1.0f / (float)max(e - s, 1);
            unsigned int pk = (unsigned int)f2h(a0 * inv) |
                              ((unsigned int)f2h(a1 * inv) << 16);
            *reinterpret_cast<unsigned int*>(&As[g][CIN + r * CIN + 2 * l2]) = pk;
        }
    }
    __syncthreads();

    // ---- phase 2: [16 x K] * [K x 64] via mfma_f32_16x16x32_f16 ----
    const int lane = tid & 63, wave = tid >> 6;   // wave owns 16-col N-tile
    const int arow = lane & 15;
    const int kb   = (lane >> 4) * 8;
    f32x4 acc = {0.f, 0.f, 0.f, 0.f};
    const unsigned short* a_ptr = &As[arow][kb];
    const unsigned short* b_ptr = &Bp[((size_t)(wave * KS) * 64 + lane) * 8];
#pragma unroll
    for (int ks = 0; ks < KS; ++ks) {
        half8 a = *reinterpret_cast<const half8*>(a_ptr + ks * 32);
        half8 b = *reinterpret_cast<const half8*>(b_ptr + (size_t)ks * 64 * 8);
        acc = __builtin_amdgcn_mfma_f32_16x16x32_f16(a, b, acc, 0, 0, 0);
    }

    // ---- epilogue: bias, (relu), BN; C layout: col=lane&15, row=(lane>>4)*4+r
    const int o = wave * 16 + (lane & 15);
    const float sc = scale[o], sh = shift[o], bi = bias[o];
#pragma unroll
    for (int r = 0; r < 4; ++r) {
        int nrow = (lane >> 4) * 4 + r;
        float t = acc[r] + bi;
        if (APPLY_RELU) t = fmaxf(t, 0.0f);
        t = t * sc + sh;
        size_t oidx = (size_t)(node0 + nrow) * 64 + o;
        if (OUT_F16) ((unsigned short*)outv)[oidx] = f2h(t);
        else         ((float*)outv)[oidx] = t;
    }
}

extern "C" void kernel_launch(void* const* d_in, const int* in_sizes, int n_in,
                              void* d_out, int out_size, void* d_ws, size_t ws_size,
                              hipStream_t stream)
{
    const int*   n_id   = (const int*)d_in[0];
    const int*   ei     = (const int*)d_in[1];   // [2, NE]
    const int*   et     = (const int*)d_in[2];   // [NE]
    const float* emb    = (const float*)d_in[3];
    const float* W1     = (const float*)d_in[4];
    const float* root1  = (const float*)d_in[5];
    const float* b1     = (const float*)d_in[6];
    const float* W2     = (const float*)d_in[7];
    const float* root2  = (const float*)d_in[8];
    const float* b2     = (const float*)d_in[9];
    const float* bn32_g = (const float*)d_in[10];
    const float* bn32_b = (const float*)d_in[11];
    const float* bn32_m = (const float*)d_in[12];
    const float* bn32_v = (const float*)d_in[13];
    const float* bn64_g = (const float*)d_in[14];
    const float* bn64_b = (const float*)d_in[15];
    const float* bn64_m = (const float*)d_in[16];
    const float* bn64_v = (const float*)d_in[17];
    const float* bnb_g  = (const float*)d_in[18];
    const float* bnb_b  = (const float*)d_in[19];
    const float* bnb_m  = (const float*)d_in[20];
    const float* bnb_v  = (const float*)d_in[21];
    float* out = (float*)d_out;

    // workspace layout (all chunks 16B-aligned)
    char* p = (char*)d_ws;
    int* cursor = (int*)p;            p += (size_t)NK * 4;
    int* off    = (int*)p;            p += (size_t)(NK + 4) * 4;
    int* bsum   = (int*)p;            p += 1024 * 4;
    int* ssrc   = (int*)p;            p += (size_t)NE * 4;
    unsigned short* x0  = (unsigned short*)p;  p += (size_t)NN * 32 * 2;
    unsigned short* h1  = (unsigned short*)p;  p += (size_t)NN * 64 * 2;
    unsigned short* Bp1 = (unsigned short*)p;  p += 4 * 9  * 64 * 8 * 2;
    unsigned short* Bp2 = (unsigned short*)p;  p += 4 * 18 * 64 * 8 * 2;
    float* sc1 = (float*)p;           p += 64 * 4;
    float* sh1 = (float*)p;           p += 64 * 4;
    float* sc2 = (float*)p;           p += 64 * 4;
    float* sh2 = (float*)p;           p += 64 * 4;

    // ---- build sorted edge structure (shared by both layers) ----
    hipMemsetAsync(cursor, 0, (size_t)NK * sizeof(int), stream);
    hist_edges<<<(NE + 255) / 256, 256, 0, stream>>>(ei, et, cursor);
    scan_blocks<<<NSB, 256, 0, stream>>>(cursor, off, bsum);
    scan_bsum<<<1, 1024, 0, stream>>>(bsum);
    scan_add<<<(NK + 256) / 256, 256, 0, stream>>>(off, bsum);
    hipMemcpyAsync(cursor, off, (size_t)NK * sizeof(int),
                   hipMemcpyDeviceToDevice, stream);
    scatter_edges<<<(NE + 255) / 256, 256, 0, stream>>>(ei, et, cursor, ssrc);

    // ---- weight/bn prep ----
    prep_scales<<<1, 64, 0, stream>>>(bn64_g, bn64_b, bn64_m, bn64_v, sc1, sh1,
                                      bnb_g, bnb_b, bnb_m, bnb_v, sc2, sh2);
    pack_B<32><<<(4 * 9 * 64 + 255) / 256, 256, 0, stream>>>(W1, root1, Bp1);
    pack_B<64><<<(4 * 18 * 64 + 255) / 256, 256, 0, stream>>>(W2, root2, Bp2);

    // ---- layer 1 ----
    compute_x0<<<(NN * 16 + 255) / 256, 256, 0, stream>>>(
        n_id, emb, bn32_g, bn32_b, bn32_m, bn32_v, (unsigned int*)x0);
    fused_layer<32, true, true><<<NN / 16, 256, 0, stream>>>(
        x0, off, ssrc, Bp1, b1, sc1, sh1, h1);

    // ---- layer 2 ----
    fused_layer<64, false, false><<<NN / 16, 256, 0, stream>>>(
        h1, off, ssrc, Bp2, b2, sc2, sh2, out);
}